// Round 6
// baseline (352.429 us; speedup 1.0000x reference)
//
#include <hip/hip_runtime.h>
#include <math.h>

#define FIELD 2097152   // 32*512*128
#define NSEQ  4096      // 32*128 sequences

typedef float f2 __attribute__((ext_vector_type(2)));   // (re, im) -> VGPR pair

__device__ __forceinline__ f2 swp(f2 a) { return __builtin_shufflevector(a, a, 1, 0); }
__device__ __forceinline__ f2 conjf2(f2 a) { return (f2){a.x, -a.y}; }
// multiply by (c + i s), with ns = (-s, s): 1 pk_mul + 1 pk_fma (swap -> op_sel)
__device__ __forceinline__ f2 cmulp(f2 a, float c, f2 ns)  { return c * a + ns * swp(a); }
// multiply by (c - i s)
__device__ __forceinline__ f2 cmulpc(f2 a, float c, f2 ns) { return c * a - ns * swp(a); }
// a + i*b  /  a - i*b
__device__ __forceinline__ f2 addi(f2 a, f2 b) { return a + (f2){-1.0f, 1.0f} * swp(b); }
__device__ __forceinline__ f2 subi(f2 a, f2 b) { return a + (f2){1.0f, -1.0f} * swp(b); }

// ---- xor-lane exchange: DPP (VALU-speed) for h in {1,2,4,8}; bpermute-based
// ---- __shfl_xor only for cross-row h in {16,32}. DS pipe runs parallel to
// ---- VALU and is TLP-hidden (r1: moving these to VALU permlane regressed).
template<int CTRL>
__device__ __forceinline__ float dpp_f(float v) {
  return __int_as_float(__builtin_amdgcn_update_dpp(
      __float_as_int(v), __float_as_int(v), CTRL, 0xF, 0xF, true));
}
template<int CTRL>
__device__ __forceinline__ float dpp0_f(float v) {   // old=0, invalid lanes -> 0
  return __int_as_float(__builtin_amdgcn_update_dpp(
      0, __float_as_int(v), CTRL, 0xF, 0xF, true));
}
template<int H>
__device__ __forceinline__ float xlane(float v) {
  if constexpr (H == 1)      return dpp_f<0xB1>(v);    // quad_perm [1,0,3,2] = xor1
  else if constexpr (H == 2) return dpp_f<0x4E>(v);    // quad_perm [2,3,0,1] = xor2
  else if constexpr (H == 4) return dpp_f<0x141>(dpp_f<0x1B>(v)); // xor7 o xor3 = xor4
  else if constexpr (H == 8) return dpp_f<0x128>(v);   // row_ror:8 = xor8
  else return __shfl_xor(v, H, 64);
}
template<int H>
__device__ __forceinline__ f2 xlane2(f2 v) {
  return (f2){xlane<H>(v.x), xlane<H>(v.y)};
}
__device__ __forceinline__ f2 shfl2(f2 v, int l) {
  return (f2){__shfl(v.x, l, 64), __shfl(v.y, l, 64)};
}
__device__ __forceinline__ float bcast0(float v) {
  return __int_as_float(__builtin_amdgcn_readfirstlane(__float_as_int(v)));
}
// 64-lane sum, zero DS ops: row_shr prefix adds + row_bcast15/31.
__device__ __forceinline__ float wave_sum(float v) {
  v += dpp0_f<0x111>(v);   // row_shr:1
  v += dpp0_f<0x112>(v);   // row_shr:2
  v += dpp0_f<0x114>(v);   // row_shr:4
  v += dpp0_f<0x118>(v);   // row_shr:8
  v += dpp0_f<0x142>(v);   // row_bcast15
  v += dpp0_f<0x143>(v);   // row_bcast31 -> lane 63 holds total
  return __int_as_float(__builtin_amdgcn_readlane(__float_as_int(v), 63));
}

// Lane-dimension butterfly stages on the per-wave 2-register set.
// Twiddles come pre-packed from planar LDS: c (b32) and wn pair (b64).
// Lane-masked: lo lanes hold (1, (0,0)); sg = +1 lo / -1 hi.
template<int H>
__device__ __forceinline__ void fwdq(f2* v, float c, f2 wn, float sg) {
#pragma unroll
  for (int b = 0; b < 2; ++b) {
    f2 p = xlane2<H>(v[b]);
    f2 t = sg * v[b] + p;          // lo: v+p ; hi: p-v
    v[b] = cmulp(t, c, wn);        // lo: *1 ; hi: *e^{-i th}
  }
}
template<int H>
__device__ __forceinline__ void invq(f2* v, float c, f2 wn, float sg) {
#pragma unroll
  for (int b = 0; b < 2; ++b) {
    f2 u = cmulpc(v[b], c, wn);    // lo: v ; hi: v*e^{+i th} (conj W)
    f2 p = xlane2<H>(u);
    v[b] = sg * u + p;             // lo: u+p ; hi: p-u
  }
}
// H==1 stage: th = (lane & 0) = 0 -> twiddle is EXACT identity; skip cmul.
__device__ __forceinline__ void fwd1(f2* v, float sg) {
#pragma unroll
  for (int b = 0; b < 2; ++b) { f2 p = xlane2<1>(v[b]); v[b] = sg * v[b] + p; }
}
__device__ __forceinline__ void inv1(f2* v, float sg) {
#pragma unroll
  for (int b = 0; b < 2; ++b) { f2 p = xlane2<1>(v[b]); v[b] = sg * v[b] + p; }
}

// Half-spectrum (this wave's 2 bins b=2j+h) -> packed-Z regs for the split
// inverse. Partner bins (4-b)&3 are intra-wave for both parities.
__device__ __forceinline__ void halfz2(f2* S, float S256, int h, int lane,
                                       int pl0, int plx,
                                       const float* twHc, const f2* twHn) {
  f2 P[2];
  P[0] = shfl2(h ? S[1] : S[0], h ? plx : pl0);
  P[1] = shfl2(h ? S[0] : S[1], plx);
  if (h == 0 && lane == 0) P[0] = (f2){S256, 0.0f};
#pragma unroll
  for (int j = 0; j < 2; ++j) {
    f2 cP = conjf2(P[j]);
    f2 A = 0.5f * (S[j] + cP);
    f2 B = 0.5f * (S[j] - cP);
    f2 Bt = cmulp(B, twHc[j], twHn[j]);   // B * e^{+i th}
    S[j] = addi(A, Bt);
  }
}

// Per-bin mode update, bitwise-identical math to the verified r0 kernel.
__device__ __forceinline__ void mode2(const f2* X, const f2* V, f2* U,
                                      const float* l1, const float* l2,
                                      float om, const float* fb) {
#pragma unroll
  for (int j = 0; j < 2; ++j) {
    float f = fb[j];
    float dfp = f - om;
    float dfm = f + om;
    float gp = __builtin_amdgcn_rcpf(fmaf(1600.0f * dfp, dfp, 1.0f));
    float gm = __builtin_amdgcn_rcpf(fmaf(1600.0f * dfm, dfm, 1.0f));
    float gs = 0.5f * (gp + gm);
    f2 D = X[j] - V[j];
    float lt = 0.25f * fmaf(l1[j], gp, l2[j] * gm);
    U[j] = gs * D + (f2){lt, 0.0f};
  }
}

// r6 = r5's 2-waves-per-sequence split with CONFLICT-FREE planar twiddles.
// r5's float4/64B-stride twiddle records were 8-way and 32-way bank
// conflicts (SQ_LDS_BANK_CONFLICT 6.67e7 = ~34% of runtime). Planar b32
// (stride 4, conflict-free) + f2 b64 (stride 8, 2-way = free, m136) arrays,
// storing the EXACT (c, sign-pair) the complex multiply consumes (zero
// per-use unpack VALU). H=1 stage twiddle is identity -> cmul skipped.
// NOTE (r5): occupancy 33->69% worked; conflicts ate it. NOTE (r4):
// registers must stay <=64 -- twiddles live in LDS, reloaded per iter
// (barriers force reload, keeping them out of the persistent set).
// NOTE (r3): op cuts alone don't move time at 4 waves -- latency-bound.
// NOTE (r2): lambda MUST stay time-domain (per-iter ifft required).
// NOTE (r1): keep cross-row exchanges on the DS pipe.
__global__ __attribute__((amdgpu_flat_work_group_size(512, 512),
                          amdgpu_waves_per_eu(8)))
void vmd_kernel(const float* __restrict__ x, float* __restrict__ out,
                float* __restrict__ ws) {
  __shared__ float stage[4 * 512];    // [seq][n]: x resident all loop; out packing in epilogue
  __shared__ float ldsLam[4 * 512];   // psi-permuted lambda per seq
  __shared__ float exchB[4 * 512];    // per-iter + epilogue slot-radix exchange
  __shared__ float csC[5 * 64];       // stage cos   (s=0..4; s=5 is identity)
  __shared__ f2    csN[5 * 64];       // stage (sn, -sn)
  __shared__ float cFC[4 * 64];       // [h*2+j][lane] slot cos
  __shared__ f2    cFN[4 * 64];       // slot (sn, -sn)
  __shared__ float cHC[4 * 64];       // [h*2+j][lane] hermitian cos
  __shared__ f2    cHN[4 * 64];       // hermitian (-sn, sn)
  __shared__ float4 omP4[4][2];       // omega partials per (seq, half)

  const int tid = threadIdx.x;
  const int wv = tid >> 6;
  const int lane = tid & 63;
  const int s = wv >> 1;              // seq within block
  const int h = wv & 1;               // half: bin parity
  const int w = (blockIdx.x >> 3) + ((blockIdx.x & 7) << 7);   // XCD swizzle
  const int g = 4 * w + s;
  const int bb = w >> 5;
  const int d0 = (4 * w) & 127;
  const int base4 = bb * 16384 + (d0 >> 2);
  float* lamS = ldsLam + s * 512;
  f2* stg2 = (f2*)stage + s * 256;    // packed (even,odd) pair view of this seq
  f2* exch2 = (f2*)exchB + s * 256;

  const int rev = (int)(__brev((unsigned)lane) >> 26);           // rev6(lane)
  const float f0 = (float)rev * (1.0f / 128.0f);
  const int plx = lane ^ 63;
  const int pl0 = (int)(__brev((unsigned)((64 - rev) & 63)) >> 26);
  const float sgh = h ? -1.0f : 1.0f;

  const int b0 = h, b1 = 2 + h;       // this wave's bins (j=0,1)
  float fb[2];
  fb[0] = f0 + (float)b0 * (1.0f / 512.0f);
  fb[1] = f0 + (float)b1 * (1.0f / 512.0f);

  // Per-stage sign (+1 lo / -1 hi), 6 VGPRs; indices compile-time constant.
  float sgR[6];
#pragma unroll
  for (int st = 0; st < 6; ++st)
    sgR[st] = (lane & (32 >> st)) ? -1.0f : 1.0f;

  // ---- block-shared twiddle fill (planar, conflict-free) ----
  if (wv < 5) {                       // stage twiddles s=0..4 (h=32>>s)
    const int hh = 32 >> wv;
    const bool hi = (lane & hh) != 0;
    float th = (float)(lane & (hh - 1)) * (3.14159265358979323846f / (float)hh);
    float sn, cs; sincosf(th, &sn, &cs);
    csC[wv * 64 + lane] = hi ? cs : 1.0f;
    csN[wv * 64 + lane] = hi ? (f2){sn, -sn} : (f2){0.0f, 0.0f};
  } else if (wv == 5) {               // slot twiddles, e^{-i th}, th=lane*b*2pi/256
#pragma unroll
    for (int hp = 0; hp < 2; ++hp)
#pragma unroll
      for (int j = 0; j < 2; ++j) {
        float th = (float)(lane * (2 * j + hp)) * 0.02454369260617026f;
        float sn, cs; sincosf(th, &sn, &cs);
        cFC[(hp * 2 + j) * 64 + lane] = cs;
        cFN[(hp * 2 + j) * 64 + lane] = (f2){sn, -sn};
      }
  } else {                            // hermitian twiddles, th=(4rev+b)*2pi/512
    const int hp = wv - 6;            // wv=6 -> h=0, wv=7 -> h=1
#pragma unroll
    for (int j = 0; j < 2; ++j) {
      float th = (float)(4 * rev + 2 * j + hp) * 0.01227184630308513f;
      float sn, cs; sincosf(th, &sn, &cs);
      cHC[(hp * 2 + j) * 64 + lane] = cs;
      cHN[(hp * 2 + j) * 64 + lane] = (f2){-sn, sn};
    }
  }

  // ---- load x: float4 (n, d0..d0+3) -> stage[seq][n]; zero lambda ----
  {
    const float4* x4 = (const float4*)x;
    float4 va = x4[base4 + tid * 32];
    stage[tid]        = va.x; stage[512 + tid]  = va.y;
    stage[1024 + tid] = va.z; stage[1536 + tid] = va.w;
    ((float4*)ldsLam)[tid] = (float4){0.0f, 0.0f, 0.0f, 0.0f};
  }
  __syncthreads();

  const float* cCl = csC + lane;
  const f2*    cNl = csN + lane;
  const float* fCl = cFC + h * 128 + lane;
  const f2*    fNl = cFN + h * 128 + lane;
  const float* hCl = cHC + h * 128 + lane;
  const f2*    hNl = cHN + h * 128 + lane;

  // ---- forward FFT, split: slot radix-4 from LDS (no exchange), then
  // ---- 6 intra-wave lane stages; twiddles from planar LDS ----
  f2 z[2];
  {
    f2 s0 = stg2[lane], s1 = stg2[64 + lane], s2 = stg2[128 + lane], s3 = stg2[192 + lane];
    if (h == 0) {
      f2 e0 = s0 + s2, e1 = s1 + s3;  // t0, t2
      z[0] = e0 + e1;                 // v0 (b=0)
      z[1] = e0 - e1;                 // v2 (b=2)
    } else {
      f2 o0 = s0 - s2, o1 = s1 - s3;  // t1, t3
      z[0] = subi(o0, o1);            // v1 (b=1)
      z[1] = addi(o0, o1);            // v3 (b=3)
    }
    z[0] = cmulp(z[0], fCl[0], fNl[0]);
    z[1] = cmulp(z[1], fCl[64], fNl[64]);
    fwdq<32>(z, cCl[0],   cNl[0],   sgR[0]);
    fwdq<16>(z, cCl[64],  cNl[64],  sgR[1]);
    fwdq<8> (z, cCl[128], cNl[128], sgR[2]);
    fwdq<4> (z, cCl[192], cNl[192], sgR[3]);
    fwdq<2> (z, cCl[256], cNl[256], sgR[4]);
    fwd1(z, sgR[5]);
  }

  // ---- Hermitian unpack -> X (this wave's 2 bins), X256 on h=0 ----
  f2 X[2];
  float X256;
  {
    float tHc[2]; f2 tHn[2];
    tHc[0] = hCl[0]; tHc[1] = hCl[64];
    tHn[0] = hNl[0]; tHn[1] = hNl[64];
    f2 P[2];
    P[0] = shfl2(h ? z[1] : z[0], h ? plx : pl0);
    P[1] = shfl2(h ? z[0] : z[1], plx);
    X256 = bcast0(z[0].x - z[0].y);   // meaningful on h=0 only
#pragma unroll
    for (int j = 0; j < 2; ++j) {
      f2 cP = conjf2(P[j]);
      f2 E = 0.5f * (z[j] + cP);
      f2 O = 0.5f * (f2){1.0f, -1.0f} * swp(z[j] - cP);   // -i*(z-cP)/2
      X[j] = E + cmulpc(O, tHc[j], tHn[j]);               // O * e^{-i th}
    }
  }

  f2 U0[2], U1[2], lam[2];
#pragma unroll
  for (int j = 0; j < 2; ++j) {
    U0[j] = (f2){0.0f, 0.0f}; U1[j] = (f2){0.0f, 0.0f}; lam[j] = (f2){0.0f, 0.0f};
  }
  float U0_256 = 0.0f, U1_256 = 0.0f;
  float om0 = 0.0f, om1 = 0.0f;

  // Loop-invariant lambda addresses (psi-permuted layout, same as r0/r4).
  const int psiW = 256 * (lane & 1) + (lane >> 1) + 64 * h;  // write base (slots 2h+j)
  const int a1_0 = 128 * b0 + 64 + rev;
  const int a1_1 = 128 * b1 + 64 + rev;
  const int a2_0 = (b0 == 0) ? (64 - rev) : (128 * (4 - b0) + 63 - rev);
  const int a2_1 = 128 * (4 - b1) + 63 - rev;

#pragma unroll 1
  for (int it = 0; it < 50; ++it) {
    float l1[2], l2[2];
    l1[0] = lamS[a1_0]; l1[1] = lamS[a1_1];
    l2[0] = lamS[a2_0]; l2[1] = lamS[a2_1];
    float lam0 = lamS[0];

    mode2(X, U1, U0, l1, l2, om0, fb);
    if (h == 0) {
      float dm = 0.5f + om0;
      float gg = __builtin_amdgcn_rcpf(fmaf(1600.0f * dm, dm, 1.0f));
      U0_256 = (X256 - U1_256 + 0.5f * lam0) * gg;
    }
    mode2(X, U0, U1, l1, l2, om1, fb);
    if (h == 0) {
      float dm = 0.5f + om1;
      float gg = __builtin_amdgcn_rcpf(fmaf(1600.0f * dm, dm, 1.0f));
      U1_256 = (X256 - U0_256 + 0.5f * lam0) * gg;
    }

    // omega partials over this wave's 2 bins, wave-reduced (pure DPP)
    float n0 = 0.0f, d0s = 0.0f, n1 = 0.0f, d1s = 0.0f;
#pragma unroll
    for (int j = 0; j < 2; ++j) {
      float f = fb[j];
      float p0 = fmaf(U0[j].x, U0[j].x, U0[j].y * U0[j].y);
      float p1 = fmaf(U1[j].x, U1[j].x, U1[j].y * U1[j].y);
      d0s += p0; n0 = fmaf(f, p0, n0);
      d1s += p1; n1 = fmaf(f, p1, n1);
    }
    n0 = wave_sum(n0); d0s = wave_sum(d0s);
    n1 = wave_sum(n1); d1s = wave_sum(d1s);

    const bool more = it < 49;
    f2 tA, tB, xa0, xa1;
    if (more) {   // split inverse FFT of S = U0+U1 up to the slot radix-4
      xa0 = stg2[h * 128 + lane];          // x slot 2h (resident in stage)
      xa1 = stg2[h * 128 + 64 + lane];     // x slot 2h+1
      float tHc[2]; f2 tHn[2];
      tHc[0] = hCl[0]; tHc[1] = hCl[64];
      tHn[0] = hNl[0]; tHn[1] = hNl[64];
      f2 zz[2];
      zz[0] = U0[0] + U1[0];
      zz[1] = U0[1] + U1[1];
      float S256 = U0_256 + U1_256;
      halfz2(zz, S256, h, lane, pl0, plx, tHc, tHn);
      inv1(zz, sgR[5]);
      invq<2> (zz, cCl[256], cNl[256], sgR[4]);
      invq<4> (zz, cCl[192], cNl[192], sgR[3]);
      invq<8> (zz, cCl[128], cNl[128], sgR[2]);
      invq<16>(zz, cCl[64],  cNl[64],  sgR[1]);
      invq<32>(zz, cCl[0],   cNl[0],   sgR[0]);
      zz[0] = cmulpc(zz[0], fCl[0], fNl[0]);
      zz[1] = cmulpc(zz[1], fCl[64], fNl[64]);
      tA = zz[0] + zz[1];   // h=0: t0 ; h=1: t2
      tB = zz[0] - zz[1];   // h=0: t1 ; h=1: t3
      exch2[h * 128 + lane]      = tA;
      exch2[h * 128 + 64 + lane] = tB;
    }
    if (lane == 0) omP4[s][h] = (float4){n0, d0s, n1, d1s};
    __syncthreads();   // omega partials + exchange halves visible
    {
      float4 pp = omP4[s][1 - h];
      om0 = (n0 + pp.x) * __builtin_amdgcn_rcpf((d0s + pp.y) + 1e-7f);
      om1 = (n1 + pp.z) * __builtin_amdgcn_rcpf((d1s + pp.w) + 1e-7f);
    }
    if (more) {
      f2 pA = exch2[(1 - h) * 128 + lane];
      f2 pB = exch2[(1 - h) * 128 + 64 + lane];
      f2 oA = pA + sgh * tA;                       // h0: t0+t2 ; h1: t0-t2
      f2 u  = h ? pB : tB;
      f2 vv = h ? tB : pB;
      f2 oB = u + sgh * (f2){-1.0f, 1.0f} * swp(vv);  // h0: t1+i*t3 ; h1: t1-i*t3
      lam[0] = lam[0] + 0.001f * (xa0 - oA * (1.0f / 256.0f));
      lam[1] = lam[1] + 0.001f * (xa1 - oB * (1.0f / 256.0f));
      lamS[psiW]            = lam[0].x;
      lamS[psiW + 128]      = lam[0].y;
      lamS[psiW + 32]       = lam[1].x;
      lamS[psiW + 32 + 128] = lam[1].y;
      __syncthreads();   // lambda visible cross-wave; exchange buffer reusable
    }
  }

  // ---- final modes: split ifft per mode, pack to stage, float4 stores ----
  float4* o4 = (float4*)out;
#pragma unroll 1
  for (int m = 0; m < 2; ++m) {
    float tHc[2]; f2 tHn[2];
    tHc[0] = hCl[0]; tHc[1] = hCl[64];
    tHn[0] = hNl[0]; tHn[1] = hNl[64];
    f2 zz[2];
    zz[0] = m ? U1[0] : U0[0];
    zz[1] = m ? U1[1] : U0[1];
    float S256 = m ? U1_256 : U0_256;
    halfz2(zz, S256, h, lane, pl0, plx, tHc, tHn);
    inv1(zz, sgR[5]);
    invq<2> (zz, cCl[256], cNl[256], sgR[4]);
    invq<4> (zz, cCl[192], cNl[192], sgR[3]);
    invq<8> (zz, cCl[128], cNl[128], sgR[2]);
    invq<16>(zz, cCl[64],  cNl[64],  sgR[1]);
    invq<32>(zz, cCl[0],   cNl[0],   sgR[0]);
    zz[0] = cmulpc(zz[0], fCl[0], fNl[0]);
    zz[1] = cmulpc(zz[1], fCl[64], fNl[64]);
    f2 tA = zz[0] + zz[1], tB = zz[0] - zz[1];
    exch2[h * 128 + lane]      = tA;
    exch2[h * 128 + 64 + lane] = tB;
    __syncthreads();
    f2 pA = exch2[(1 - h) * 128 + lane];
    f2 pB = exch2[(1 - h) * 128 + 64 + lane];
    f2 oA = pA + sgh * tA;
    f2 u  = h ? pB : tB;
    f2 vv = h ? tB : pB;
    f2 oB = u + sgh * (f2){-1.0f, 1.0f} * swp(vv);
    stg2[64 * (2 * h + 0) + lane] = oA * (1.0f / 256.0f);
    stg2[64 * (2 * h + 1) + lane] = oB * (1.0f / 256.0f);
    __syncthreads();
    float4 v;
    v.x = stage[tid]; v.y = stage[512 + tid];
    v.z = stage[1024 + tid]; v.w = stage[1536 + tid];
    o4[(m + 1) * (FIELD / 4) + base4 + tid * 32] = v;
    __syncthreads();   // stage reuse barrier for the next mode
  }

  if (lane == 0 && h == 0) {
    ws[g] = om0;             // omega staging in workspace (read-only for epi)
    ws[NSEQ + g] = om1;
  }
}

// Fused epilogue: per-batch flag recomputed per block (64 ws reads + wave
// reduce), trend slice zeroed, period/res conditionally swapped.
__global__ __launch_bounds__(256) void epi_kernel(float* __restrict__ out,
                                                  const float* __restrict__ ws) {
  const int tid = threadIdx.x;
  const int blk = blockIdx.x;          // 0..2047; 64 blocks per batch
  const int bb = blk >> 6;
  __shared__ float flagS;
  if (tid < 64) {
    float o0 = ws[bb * 128 + tid] + ws[bb * 128 + 64 + tid];
    float o1 = ws[NSEQ + bb * 128 + tid] + ws[NSEQ + bb * 128 + 64 + tid];
#pragma unroll
    for (int off = 32; off >= 1; off >>= 1) {
      o0 += __shfl_xor(o0, off, 64);
      o1 += __shfl_xor(o1, off, 64);
    }
    if (tid == 0) flagS = (o0 > o1) ? 1.0f : 0.0f;   // swap iff mean0 > mean1
  }
  __syncthreads();
  const bool sw = flagS > 0.5f;
  float4* o4 = (float4*)out;
  const int i = blk * 256 + tid;       // float4 index within trend field
  o4[i] = (float4){0.0f, 0.0f, 0.0f, 0.0f};
  if (sw) {
    float4 p = o4[FIELD / 4 + i];
    float4 r = o4[2 * FIELD / 4 + i];
    o4[FIELD / 4 + i] = r;
    o4[2 * FIELD / 4 + i] = p;
  }
}

extern "C" void kernel_launch(void* const* d_in, const int* in_sizes, int n_in,
                              void* d_out, int out_size, void* d_ws, size_t ws_size,
                              hipStream_t stream) {
  (void)in_sizes; (void)n_in; (void)ws_size; (void)out_size;
  const float* x = (const float*)d_in[0];
  float* out = (float*)d_out;
  float* ws = (float*)d_ws;
  vmd_kernel<<<NSEQ / 4, 512, 0, stream>>>(x, out, ws);
  epi_kernel<<<FIELD / 1024, 256, 0, stream>>>(out, ws);
}

// Round 7
// 283.427 us; speedup vs baseline: 1.2435x; 1.2435x over previous
//
#include <hip/hip_runtime.h>
#include <math.h>

#define FIELD 2097152   // 32*512*128
#define NSEQ  4096      // 32*128 sequences

typedef float f2 __attribute__((ext_vector_type(2)));   // (re, im) -> VGPR pair

__device__ __forceinline__ f2 swp(f2 a) { return __builtin_shufflevector(a, a, 1, 0); }
__device__ __forceinline__ f2 conjf2(f2 a) { return (f2){a.x, -a.y}; }
// multiply by (c + i s), with ns = (-s, s): 1 pk_mul + 1 pk_fma (swap -> op_sel)
__device__ __forceinline__ f2 cmulp(f2 a, float c, f2 ns)  { return c * a + ns * swp(a); }
// multiply by (c - i s)
__device__ __forceinline__ f2 cmulpc(f2 a, float c, f2 ns) { return c * a - ns * swp(a); }
// a + i*b  /  a - i*b
__device__ __forceinline__ f2 addi(f2 a, f2 b) { return a + (f2){-1.0f, 1.0f} * swp(b); }
__device__ __forceinline__ f2 subi(f2 a, f2 b) { return a + (f2){1.0f, -1.0f} * swp(b); }

// ---- xor-lane exchange: DPP (VALU-speed) for h in {1,2,4,8}; bpermute-based
// ---- __shfl_xor only for cross-row h in {16,32}. DS pipe runs parallel to
// ---- VALU and is TLP-hidden (r1: moving these to VALU permlane regressed).
template<int CTRL>
__device__ __forceinline__ float dpp_f(float v) {
  return __int_as_float(__builtin_amdgcn_update_dpp(
      __float_as_int(v), __float_as_int(v), CTRL, 0xF, 0xF, true));
}
template<int CTRL>
__device__ __forceinline__ float dpp0_f(float v) {   // old=0, invalid lanes -> 0
  return __int_as_float(__builtin_amdgcn_update_dpp(
      0, __float_as_int(v), CTRL, 0xF, 0xF, true));
}
template<int H>
__device__ __forceinline__ float xlane(float v) {
  if constexpr (H == 1)      return dpp_f<0xB1>(v);    // quad_perm [1,0,3,2] = xor1
  else if constexpr (H == 2) return dpp_f<0x4E>(v);    // quad_perm [2,3,0,1] = xor2
  else if constexpr (H == 4) return dpp_f<0x141>(dpp_f<0x1B>(v)); // xor7 o xor3 = xor4
  else if constexpr (H == 8) return dpp_f<0x128>(v);   // row_ror:8 = xor8
  else return __shfl_xor(v, H, 64);
}
template<int H>
__device__ __forceinline__ f2 xlane2(f2 v) {
  return (f2){xlane<H>(v.x), xlane<H>(v.y)};
}
__device__ __forceinline__ f2 shfl2(f2 v, int l) {
  return (f2){__shfl(v.x, l, 64), __shfl(v.y, l, 64)};
}
__device__ __forceinline__ float bcast0(float v) {
  return __int_as_float(__builtin_amdgcn_readfirstlane(__float_as_int(v)));
}
// 64-lane sum, zero DS ops: row_shr prefix adds + row_bcast15/31.
__device__ __forceinline__ float wave_sum(float v) {
  v += dpp0_f<0x111>(v);   // row_shr:1
  v += dpp0_f<0x112>(v);   // row_shr:2
  v += dpp0_f<0x114>(v);   // row_shr:4
  v += dpp0_f<0x118>(v);   // row_shr:8
  v += dpp0_f<0x142>(v);   // row_bcast15
  v += dpp0_f<0x143>(v);   // row_bcast31 -> lane 63 holds total
  return __int_as_float(__builtin_amdgcn_readlane(__float_as_int(v), 63));
}

// Lane-dimension butterfly stages on the per-wave 2-register set.
// Twiddles come pre-packed from planar LDS: c (b32) and wn pair (b64).
// Lane-masked: lo lanes hold (1, (0,0)); sg = +1 lo / -1 hi.
template<int H>
__device__ __forceinline__ void fwdq(f2* v, float c, f2 wn, float sg) {
#pragma unroll
  for (int b = 0; b < 2; ++b) {
    f2 p = xlane2<H>(v[b]);
    f2 t = sg * v[b] + p;          // lo: v+p ; hi: p-v
    v[b] = cmulp(t, c, wn);        // lo: *1 ; hi: *e^{-i th}
  }
}
template<int H>
__device__ __forceinline__ void invq(f2* v, float c, f2 wn, float sg) {
#pragma unroll
  for (int b = 0; b < 2; ++b) {
    f2 u = cmulpc(v[b], c, wn);    // lo: v ; hi: v*e^{+i th} (conj W)
    f2 p = xlane2<H>(u);
    v[b] = sg * u + p;             // lo: u+p ; hi: p-u
  }
}
// H==1 stage: th = (lane & 0) = 0 -> twiddle is EXACT identity; skip cmul.
__device__ __forceinline__ void fwd1(f2* v, float sg) {
#pragma unroll
  for (int b = 0; b < 2; ++b) { f2 p = xlane2<1>(v[b]); v[b] = sg * v[b] + p; }
}
__device__ __forceinline__ void inv1(f2* v, float sg) {
#pragma unroll
  for (int b = 0; b < 2; ++b) { f2 p = xlane2<1>(v[b]); v[b] = sg * v[b] + p; }
}

// Half-spectrum (this wave's 2 bins b=2j+h) -> packed-Z regs for the split
// inverse. Partner bins (4-b)&3 are intra-wave for both parities.
__device__ __forceinline__ void halfz2(f2* S, float S256, int h, int lane,
                                       int pl0, int plx,
                                       const float* twHc, const f2* twHn) {
  f2 P[2];
  P[0] = shfl2(h ? S[1] : S[0], h ? plx : pl0);
  P[1] = shfl2(h ? S[0] : S[1], plx);
  if (h == 0 && lane == 0) P[0] = (f2){S256, 0.0f};
#pragma unroll
  for (int j = 0; j < 2; ++j) {
    f2 cP = conjf2(P[j]);
    f2 A = 0.5f * (S[j] + cP);
    f2 B = 0.5f * (S[j] - cP);
    f2 Bt = cmulp(B, twHc[j], twHn[j]);   // B * e^{+i th}
    S[j] = addi(A, Bt);
  }
}

// Per-bin mode update, bitwise-identical math to the verified r0 kernel.
__device__ __forceinline__ void mode2(const f2* X, const f2* V, f2* U,
                                      const float* l1, const float* l2,
                                      float om, const float* fb) {
#pragma unroll
  for (int j = 0; j < 2; ++j) {
    float f = fb[j];
    float dfp = f - om;
    float dfm = f + om;
    float gp = __builtin_amdgcn_rcpf(fmaf(1600.0f * dfp, dfp, 1.0f));
    float gm = __builtin_amdgcn_rcpf(fmaf(1600.0f * dfm, dfm, 1.0f));
    float gs = 0.5f * (gp + gm);
    f2 D = X[j] - V[j];
    float lt = 0.25f * fmaf(l1[j], gp, l2[j] * gm);
    U[j] = gs * D + (f2){lt, 0.0f};
  }
}

// r7 = r6 (2-waves/seq split, conflict-free planar twiddles) with the
// REGISTER ALLOCATION PINNED: amdgpu_num_vgpr(64) replaces waves_per_eu(8).
// r6 proved conflicts fixed (6.5e6) + occupancy 83%, but the allocator
// chose 32 VGPRs and spilled 323 MB/dispatch of scratch (VALUBusy 56%).
// 64 VGPRs is the 8-waves/SIMD step (m69); LDS (34.8 KB -> 4 blocks/CU)
// still allows 32 waves/CU. x re-reads moved next to their only use
// (after the barrier) to shorten live ranges for the allocator.
// GATE: if FETCH > 50 MB or vmd >= 250 us, the split is falsified ->
// revert to the r3 structure next round.
// NOTE (r5): float4/64B-stride twiddle records = 8/32-way bank conflicts.
// NOTE (r3): op cuts alone don't move time at 4 waves -- latency-bound.
// NOTE (r2): lambda MUST stay time-domain (per-iter ifft required).
// NOTE (r1): keep cross-row exchanges on the DS pipe.
__global__ __attribute__((amdgpu_flat_work_group_size(512, 512),
                          amdgpu_num_vgpr(64)))
void vmd_kernel(const float* __restrict__ x, float* __restrict__ out,
                float* __restrict__ ws) {
  __shared__ float stage[4 * 512];    // [seq][n]: x resident all loop; out packing in epilogue
  __shared__ float ldsLam[4 * 512];   // psi-permuted lambda per seq
  __shared__ float exchB[4 * 512];    // per-iter + epilogue slot-radix exchange
  __shared__ float csC[5 * 64];       // stage cos   (s=0..4; s=5 is identity)
  __shared__ f2    csN[5 * 64];       // stage (sn, -sn)
  __shared__ float cFC[4 * 64];       // [h*2+j][lane] slot cos
  __shared__ f2    cFN[4 * 64];       // slot (sn, -sn)
  __shared__ float cHC[4 * 64];       // [h*2+j][lane] hermitian cos
  __shared__ f2    cHN[4 * 64];       // hermitian (-sn, sn)
  __shared__ float4 omP4[4][2];       // omega partials per (seq, half)

  const int tid = threadIdx.x;
  const int wv = tid >> 6;
  const int lane = tid & 63;
  const int s = wv >> 1;              // seq within block
  const int h = wv & 1;               // half: bin parity
  const int w = (blockIdx.x >> 3) + ((blockIdx.x & 7) << 7);   // XCD swizzle
  const int g = 4 * w + s;
  const int bb = w >> 5;
  const int d0 = (4 * w) & 127;
  const int base4 = bb * 16384 + (d0 >> 2);
  float* lamS = ldsLam + s * 512;
  f2* stg2 = (f2*)stage + s * 256;    // packed (even,odd) pair view of this seq
  f2* exch2 = (f2*)exchB + s * 256;

  const int rev = (int)(__brev((unsigned)lane) >> 26);           // rev6(lane)
  const float f0 = (float)rev * (1.0f / 128.0f);
  const int plx = lane ^ 63;
  const int pl0 = (int)(__brev((unsigned)((64 - rev) & 63)) >> 26);
  const float sgh = h ? -1.0f : 1.0f;

  const int b0 = h, b1 = 2 + h;       // this wave's bins (j=0,1)
  float fb[2];
  fb[0] = f0 + (float)b0 * (1.0f / 512.0f);
  fb[1] = f0 + (float)b1 * (1.0f / 512.0f);

  // Per-stage sign (+1 lo / -1 hi), 6 VGPRs; indices compile-time constant.
  float sgR[6];
#pragma unroll
  for (int st = 0; st < 6; ++st)
    sgR[st] = (lane & (32 >> st)) ? -1.0f : 1.0f;

  // ---- block-shared twiddle fill (planar, conflict-free) ----
  if (wv < 5) {                       // stage twiddles s=0..4 (h=32>>s)
    const int hh = 32 >> wv;
    const bool hi = (lane & hh) != 0;
    float th = (float)(lane & (hh - 1)) * (3.14159265358979323846f / (float)hh);
    float sn, cs; sincosf(th, &sn, &cs);
    csC[wv * 64 + lane] = hi ? cs : 1.0f;
    csN[wv * 64 + lane] = hi ? (f2){sn, -sn} : (f2){0.0f, 0.0f};
  } else if (wv == 5) {               // slot twiddles, e^{-i th}, th=lane*b*2pi/256
#pragma unroll
    for (int hp = 0; hp < 2; ++hp)
#pragma unroll
      for (int j = 0; j < 2; ++j) {
        float th = (float)(lane * (2 * j + hp)) * 0.02454369260617026f;
        float sn, cs; sincosf(th, &sn, &cs);
        cFC[(hp * 2 + j) * 64 + lane] = cs;
        cFN[(hp * 2 + j) * 64 + lane] = (f2){sn, -sn};
      }
  } else {                            // hermitian twiddles, th=(4rev+b)*2pi/512
    const int hp = wv - 6;            // wv=6 -> h=0, wv=7 -> h=1
#pragma unroll
    for (int j = 0; j < 2; ++j) {
      float th = (float)(4 * rev + 2 * j + hp) * 0.01227184630308513f;
      float sn, cs; sincosf(th, &sn, &cs);
      cHC[(hp * 2 + j) * 64 + lane] = cs;
      cHN[(hp * 2 + j) * 64 + lane] = (f2){-sn, sn};
    }
  }

  // ---- load x: float4 (n, d0..d0+3) -> stage[seq][n]; zero lambda ----
  {
    const float4* x4 = (const float4*)x;
    float4 va = x4[base4 + tid * 32];
    stage[tid]        = va.x; stage[512 + tid]  = va.y;
    stage[1024 + tid] = va.z; stage[1536 + tid] = va.w;
    ((float4*)ldsLam)[tid] = (float4){0.0f, 0.0f, 0.0f, 0.0f};
  }
  __syncthreads();

  const float* cCl = csC + lane;
  const f2*    cNl = csN + lane;
  const float* fCl = cFC + h * 128 + lane;
  const f2*    fNl = cFN + h * 128 + lane;
  const float* hCl = cHC + h * 128 + lane;
  const f2*    hNl = cHN + h * 128 + lane;

  // ---- forward FFT, split: slot radix-4 from LDS (no exchange), then
  // ---- 6 intra-wave lane stages; twiddles from planar LDS ----
  f2 z[2];
  {
    f2 s0 = stg2[lane], s1 = stg2[64 + lane], s2 = stg2[128 + lane], s3 = stg2[192 + lane];
    if (h == 0) {
      f2 e0 = s0 + s2, e1 = s1 + s3;  // t0, t2
      z[0] = e0 + e1;                 // v0 (b=0)
      z[1] = e0 - e1;                 // v2 (b=2)
    } else {
      f2 o0 = s0 - s2, o1 = s1 - s3;  // t1, t3
      z[0] = subi(o0, o1);            // v1 (b=1)
      z[1] = addi(o0, o1);            // v3 (b=3)
    }
    z[0] = cmulp(z[0], fCl[0], fNl[0]);
    z[1] = cmulp(z[1], fCl[64], fNl[64]);
    fwdq<32>(z, cCl[0],   cNl[0],   sgR[0]);
    fwdq<16>(z, cCl[64],  cNl[64],  sgR[1]);
    fwdq<8> (z, cCl[128], cNl[128], sgR[2]);
    fwdq<4> (z, cCl[192], cNl[192], sgR[3]);
    fwdq<2> (z, cCl[256], cNl[256], sgR[4]);
    fwd1(z, sgR[5]);
  }

  // ---- Hermitian unpack -> X (this wave's 2 bins), X256 on h=0 ----
  f2 X[2];
  float X256;
  {
    float tHc[2]; f2 tHn[2];
    tHc[0] = hCl[0]; tHc[1] = hCl[64];
    tHn[0] = hNl[0]; tHn[1] = hNl[64];
    f2 P[2];
    P[0] = shfl2(h ? z[1] : z[0], h ? plx : pl0);
    P[1] = shfl2(h ? z[0] : z[1], plx);
    X256 = bcast0(z[0].x - z[0].y);   // meaningful on h=0 only
#pragma unroll
    for (int j = 0; j < 2; ++j) {
      f2 cP = conjf2(P[j]);
      f2 E = 0.5f * (z[j] + cP);
      f2 O = 0.5f * (f2){1.0f, -1.0f} * swp(z[j] - cP);   // -i*(z-cP)/2
      X[j] = E + cmulpc(O, tHc[j], tHn[j]);               // O * e^{-i th}
    }
  }

  f2 U0[2], U1[2], lam[2];
#pragma unroll
  for (int j = 0; j < 2; ++j) {
    U0[j] = (f2){0.0f, 0.0f}; U1[j] = (f2){0.0f, 0.0f}; lam[j] = (f2){0.0f, 0.0f};
  }
  float U0_256 = 0.0f, U1_256 = 0.0f;
  float om0 = 0.0f, om1 = 0.0f;

  // Loop-invariant lambda addresses (psi-permuted layout, same as r0/r4).
  const int psiW = 256 * (lane & 1) + (lane >> 1) + 64 * h;  // write base (slots 2h+j)
  const int a1_0 = 128 * b0 + 64 + rev;
  const int a1_1 = 128 * b1 + 64 + rev;
  const int a2_0 = (b0 == 0) ? (64 - rev) : (128 * (4 - b0) + 63 - rev);
  const int a2_1 = 128 * (4 - b1) + 63 - rev;

#pragma unroll 1
  for (int it = 0; it < 50; ++it) {
    float l1[2], l2[2];
    l1[0] = lamS[a1_0]; l1[1] = lamS[a1_1];
    l2[0] = lamS[a2_0]; l2[1] = lamS[a2_1];
    float lam0 = lamS[0];

    mode2(X, U1, U0, l1, l2, om0, fb);
    if (h == 0) {
      float dm = 0.5f + om0;
      float gg = __builtin_amdgcn_rcpf(fmaf(1600.0f * dm, dm, 1.0f));
      U0_256 = (X256 - U1_256 + 0.5f * lam0) * gg;
    }
    mode2(X, U0, U1, l1, l2, om1, fb);
    if (h == 0) {
      float dm = 0.5f + om1;
      float gg = __builtin_amdgcn_rcpf(fmaf(1600.0f * dm, dm, 1.0f));
      U1_256 = (X256 - U0_256 + 0.5f * lam0) * gg;
    }

    // omega partials over this wave's 2 bins, wave-reduced (pure DPP)
    float n0 = 0.0f, d0s = 0.0f, n1 = 0.0f, d1s = 0.0f;
#pragma unroll
    for (int j = 0; j < 2; ++j) {
      float f = fb[j];
      float p0 = fmaf(U0[j].x, U0[j].x, U0[j].y * U0[j].y);
      float p1 = fmaf(U1[j].x, U1[j].x, U1[j].y * U1[j].y);
      d0s += p0; n0 = fmaf(f, p0, n0);
      d1s += p1; n1 = fmaf(f, p1, n1);
    }
    n0 = wave_sum(n0); d0s = wave_sum(d0s);
    n1 = wave_sum(n1); d1s = wave_sum(d1s);

    const bool more = it < 49;
    f2 tA, tB;
    if (more) {   // split inverse FFT of S = U0+U1 up to the slot radix-4
      float tHc[2]; f2 tHn[2];
      tHc[0] = hCl[0]; tHc[1] = hCl[64];
      tHn[0] = hNl[0]; tHn[1] = hNl[64];
      f2 zz[2];
      zz[0] = U0[0] + U1[0];
      zz[1] = U0[1] + U1[1];
      float S256 = U0_256 + U1_256;
      halfz2(zz, S256, h, lane, pl0, plx, tHc, tHn);
      inv1(zz, sgR[5]);
      invq<2> (zz, cCl[256], cNl[256], sgR[4]);
      invq<4> (zz, cCl[192], cNl[192], sgR[3]);
      invq<8> (zz, cCl[128], cNl[128], sgR[2]);
      invq<16>(zz, cCl[64],  cNl[64],  sgR[1]);
      invq<32>(zz, cCl[0],   cNl[0],   sgR[0]);
      zz[0] = cmulpc(zz[0], fCl[0], fNl[0]);
      zz[1] = cmulpc(zz[1], fCl[64], fNl[64]);
      tA = zz[0] + zz[1];   // h=0: t0 ; h=1: t2
      tB = zz[0] - zz[1];   // h=0: t1 ; h=1: t3
      exch2[h * 128 + lane]      = tA;
      exch2[h * 128 + 64 + lane] = tB;
    }
    if (lane == 0) omP4[s][h] = (float4){n0, d0s, n1, d1s};
    __syncthreads();   // omega partials + exchange halves visible
    {
      float4 pp = omP4[s][1 - h];
      om0 = (n0 + pp.x) * __builtin_amdgcn_rcpf((d0s + pp.y) + 1e-7f);
      om1 = (n1 + pp.z) * __builtin_amdgcn_rcpf((d1s + pp.w) + 1e-7f);
    }
    if (more) {
      f2 pA = exch2[(1 - h) * 128 + lane];
      f2 pB = exch2[(1 - h) * 128 + 64 + lane];
      f2 xa0 = stg2[h * 128 + lane];          // x slot 2h (read at use site)
      f2 xa1 = stg2[h * 128 + 64 + lane];     // x slot 2h+1
      f2 oA = pA + sgh * tA;                       // h0: t0+t2 ; h1: t0-t2
      f2 u  = h ? pB : tB;
      f2 vv = h ? tB : pB;
      f2 oB = u + sgh * (f2){-1.0f, 1.0f} * swp(vv);  // h0: t1+i*t3 ; h1: t1-i*t3
      lam[0] = lam[0] + 0.001f * (xa0 - oA * (1.0f / 256.0f));
      lam[1] = lam[1] + 0.001f * (xa1 - oB * (1.0f / 256.0f));
      lamS[psiW]            = lam[0].x;
      lamS[psiW + 128]      = lam[0].y;
      lamS[psiW + 32]       = lam[1].x;
      lamS[psiW + 32 + 128] = lam[1].y;
      __syncthreads();   // lambda visible cross-wave; exchange buffer reusable
    }
  }

  // ---- final modes: split ifft per mode, pack to stage, float4 stores ----
  float4* o4 = (float4*)out;
#pragma unroll 1
  for (int m = 0; m < 2; ++m) {
    float tHc[2]; f2 tHn[2];
    tHc[0] = hCl[0]; tHc[1] = hCl[64];
    tHn[0] = hNl[0]; tHn[1] = hNl[64];
    f2 zz[2];
    zz[0] = m ? U1[0] : U0[0];
    zz[1] = m ? U1[1] : U0[1];
    float S256 = m ? U1_256 : U0_256;
    halfz2(zz, S256, h, lane, pl0, plx, tHc, tHn);
    inv1(zz, sgR[5]);
    invq<2> (zz, cCl[256], cNl[256], sgR[4]);
    invq<4> (zz, cCl[192], cNl[192], sgR[3]);
    invq<8> (zz, cCl[128], cNl[128], sgR[2]);
    invq<16>(zz, cCl[64],  cNl[64],  sgR[1]);
    invq<32>(zz, cCl[0],   cNl[0],   sgR[0]);
    zz[0] = cmulpc(zz[0], fCl[0], fNl[0]);
    zz[1] = cmulpc(zz[1], fCl[64], fNl[64]);
    f2 tA = zz[0] + zz[1], tB = zz[0] - zz[1];
    exch2[h * 128 + lane]      = tA;
    exch2[h * 128 + 64 + lane] = tB;
    __syncthreads();
    f2 pA = exch2[(1 - h) * 128 + lane];
    f2 pB = exch2[(1 - h) * 128 + 64 + lane];
    f2 oA = pA + sgh * tA;
    f2 u  = h ? pB : tB;
    f2 vv = h ? tB : pB;
    f2 oB = u + sgh * (f2){-1.0f, 1.0f} * swp(vv);
    stg2[64 * (2 * h + 0) + lane] = oA * (1.0f / 256.0f);
    stg2[64 * (2 * h + 1) + lane] = oB * (1.0f / 256.0f);
    __syncthreads();
    float4 v;
    v.x = stage[tid]; v.y = stage[512 + tid];
    v.z = stage[1024 + tid]; v.w = stage[1536 + tid];
    o4[(m + 1) * (FIELD / 4) + base4 + tid * 32] = v;
    __syncthreads();   // stage reuse barrier for the next mode
  }

  if (lane == 0 && h == 0) {
    ws[g] = om0;             // omega staging in workspace (read-only for epi)
    ws[NSEQ + g] = om1;
  }
}

// Fused epilogue: per-batch flag recomputed per block (64 ws reads + wave
// reduce), trend slice zeroed, period/res conditionally swapped.
__global__ __launch_bounds__(256) void epi_kernel(float* __restrict__ out,
                                                  const float* __restrict__ ws) {
  const int tid = threadIdx.x;
  const int blk = blockIdx.x;          // 0..2047; 64 blocks per batch
  const int bb = blk >> 6;
  __shared__ float flagS;
  if (tid < 64) {
    float o0 = ws[bb * 128 + tid] + ws[bb * 128 + 64 + tid];
    float o1 = ws[NSEQ + bb * 128 + tid] + ws[NSEQ + bb * 128 + 64 + tid];
#pragma unroll
    for (int off = 32; off >= 1; off >>= 1) {
      o0 += __shfl_xor(o0, off, 64);
      o1 += __shfl_xor(o1, off, 64);
    }
    if (tid == 0) flagS = (o0 > o1) ? 1.0f : 0.0f;   // swap iff mean0 > mean1
  }
  __syncthreads();
  const bool sw = flagS > 0.5f;
  float4* o4 = (float4*)out;
  const int i = blk * 256 + tid;       // float4 index within trend field
  o4[i] = (float4){0.0f, 0.0f, 0.0f, 0.0f};
  if (sw) {
    float4 p = o4[FIELD / 4 + i];
    float4 r = o4[2 * FIELD / 4 + i];
    o4[FIELD / 4 + i] = r;
    o4[2 * FIELD / 4 + i] = p;
  }
}

extern "C" void kernel_launch(void* const* d_in, const int* in_sizes, int n_in,
                              void* d_out, int out_size, void* d_ws, size_t ws_size,
                              hipStream_t stream) {
  (void)in_sizes; (void)n_in; (void)ws_size; (void)out_size;
  const float* x = (const float*)d_in[0];
  float* out = (float*)d_out;
  float* ws = (float*)d_ws;
  vmd_kernel<<<NSEQ / 4, 512, 0, stream>>>(x, out, ws);
  epi_kernel<<<FIELD / 1024, 256, 0, stream>>>(out, ws);
}

// Round 8
// 230.455 us; speedup vs baseline: 1.5293x; 1.2299x over previous
//
#include <hip/hip_runtime.h>
#include <math.h>

#define FIELD 2097152   // 32*512*128
#define NSEQ  4096      // 32*128 sequences

typedef float f2 __attribute__((ext_vector_type(2)));   // (re, im) -> VGPR pair

__device__ __forceinline__ f2 swp(f2 a) { return __builtin_shufflevector(a, a, 1, 0); }
__device__ __forceinline__ f2 conjf2(f2 a) { return (f2){a.x, -a.y}; }
// multiply by (c + i s), with ns = (-s, s): 1 pk_mul + 1 pk_fma (swap -> op_sel)
__device__ __forceinline__ f2 cmulp(f2 a, float c, f2 ns)  { return c * a + ns * swp(a); }
// multiply by (c - i s)
__device__ __forceinline__ f2 cmulpc(f2 a, float c, f2 ns) { return c * a - ns * swp(a); }
// a + i*b  /  a - i*b
__device__ __forceinline__ f2 addi(f2 a, f2 b) { return a + (f2){-1.0f, 1.0f} * swp(b); }
__device__ __forceinline__ f2 subi(f2 a, f2 b) { return a + (f2){1.0f, -1.0f} * swp(b); }

// ---- xor-lane exchange: DPP (VALU-speed) for h in {1,2,4,8}; bpermute-based
// ---- __shfl_xor only for cross-row h in {16,32}. All 64 lanes active.
// ---- (r1: moving these onto VALU permlane REGRESSED +24us -- DS pipe is
// ---- parallel to VALU and TLP-hidden; VALU issue is the scarce resource.)
template<int CTRL>
__device__ __forceinline__ float dpp_f(float v) {
  return __int_as_float(__builtin_amdgcn_update_dpp(
      __float_as_int(v), __float_as_int(v), CTRL, 0xF, 0xF, true));
}
template<int CTRL>
__device__ __forceinline__ float dpp0_f(float v) {   // old=0, invalid lanes -> 0
  return __int_as_float(__builtin_amdgcn_update_dpp(
      0, __float_as_int(v), CTRL, 0xF, 0xF, true));
}
template<int H>
__device__ __forceinline__ float xlane(float v) {
  if constexpr (H == 1)      return dpp_f<0xB1>(v);    // quad_perm [1,0,3,2] = xor1
  else if constexpr (H == 2) return dpp_f<0x4E>(v);    // quad_perm [2,3,0,1] = xor2
  else if constexpr (H == 4) return dpp_f<0x141>(dpp_f<0x1B>(v)); // xor7 o xor3 = xor4
  else if constexpr (H == 8) return dpp_f<0x128>(v);   // row_ror:8 = xor8
  else return __shfl_xor(v, H, 64);
}
template<int H>
__device__ __forceinline__ f2 xlane2(f2 v) {
  return (f2){xlane<H>(v.x), xlane<H>(v.y)};
}
__device__ __forceinline__ f2 shfl2(f2 v, int l) {
  return (f2){__shfl(v.x, l, 64), __shfl(v.y, l, 64)};
}
__device__ __forceinline__ float bcast0(float v) {
  return __int_as_float(__builtin_amdgcn_readfirstlane(__float_as_int(v)));
}
// 64-lane sum, zero DS ops: row_shr prefix adds + row_bcast15/31.
__device__ __forceinline__ float wave_sum(float v) {
  v += dpp0_f<0x111>(v);   // row_shr:1
  v += dpp0_f<0x112>(v);   // row_shr:2
  v += dpp0_f<0x114>(v);   // row_shr:4
  v += dpp0_f<0x118>(v);   // row_shr:8
  v += dpp0_f<0x142>(v);   // row_bcast15
  v += dpp0_f<0x143>(v);   // row_bcast31 -> lane 63 holds total
  return __int_as_float(__builtin_amdgcn_readlane(__float_as_int(v), 63));
}

__device__ __forceinline__ void fft4_fwd(f2* v) {
  f2 t0 = v[0] + v[2], t1 = v[0] - v[2];
  f2 t2 = v[1] + v[3], t3 = v[1] - v[3];
  v[0] = t0 + t2; v[2] = t0 - t2;
  v[1] = subi(t1, t3);
  v[3] = addi(t1, t3);
}
__device__ __forceinline__ void fft4_inv(f2* v) {
  f2 t0 = v[0] + v[2], t1 = v[0] - v[2];
  f2 t2 = v[1] + v[3], t3 = v[1] - v[3];
  v[0] = t0 + t2; v[2] = t0 - t2;
  v[1] = addi(t1, t3);
  v[3] = subi(t1, t3);
}

// Butterfly stages with LANE-MASKED twiddles (lo lanes hold W=(1,0): no
// cndmask selects anywhere). sg = +1 lo / -1 hi.
template<int H>
__device__ __forceinline__ void fwd_stage(f2* v, float wr, f2 wn, float sg) {
#pragma unroll
  for (int b = 0; b < 4; ++b) {
    f2 p = xlane2<H>(v[b]);
    f2 t = sg * v[b] + p;          // lo: v+p ; hi: p-v
    v[b] = cmulp(t, wr, wn);       // lo: *1 ; hi: *e^{-i th}
  }
}
template<int H>
__device__ __forceinline__ void inv_stage(f2* v, float wr, f2 wn, float sg) {
#pragma unroll
  for (int b = 0; b < 4; ++b) {
    f2 u = cmulpc(v[b], wr, wn);   // lo: v ; hi: v*e^{+i th} (conj W)
    f2 p = xlane2<H>(u);
    v[b] = sg * u + p;             // lo: u+p ; hi: p-u
  }
}

// 256-point FFT: time n = 64a+lane (slot a) <-> freq k = 4*rev6(lane)+b.
__device__ __forceinline__ void fft256_fwd(f2* v,
                                           const float* twFc, const f2* twFn,
                                           const float* wrS, const f2* wnS,
                                           const float* sgS) {
  fft4_fwd(v);
#pragma unroll
  for (int b = 1; b < 4; ++b) v[b] = cmulp(v[b], twFc[b-1], twFn[b-1]);
  fwd_stage<32>(v, wrS[0], wnS[0], sgS[0]);
  fwd_stage<16>(v, wrS[1], wnS[1], sgS[1]);
  fwd_stage<8> (v, wrS[2], wnS[2], sgS[2]);
  fwd_stage<4> (v, wrS[3], wnS[3], sgS[3]);
  fwd_stage<2> (v, wrS[4], wnS[4], sgS[4]);
  fwd_stage<1> (v, wrS[5], wnS[5], sgS[5]);
}

__device__ __forceinline__ void ifft256(f2* v,
                                        const float* twFc, const f2* twFn,
                                        const float* wrS, const f2* wnS,
                                        const float* sgS) {
  inv_stage<1> (v, wrS[5], wnS[5], sgS[5]);
  inv_stage<2> (v, wrS[4], wnS[4], sgS[4]);
  inv_stage<4> (v, wrS[3], wnS[3], sgS[3]);
  inv_stage<8> (v, wrS[2], wnS[2], sgS[2]);
  inv_stage<16>(v, wrS[1], wnS[1], sgS[1]);
  inv_stage<32>(v, wrS[0], wnS[0], sgS[0]);
#pragma unroll
  for (int b = 1; b < 4; ++b) v[b] = cmulpc(v[b], twFc[b-1], twFn[b-1]);
  fft4_inv(v);
}

// Half-spectrum S[0..255] (+ real scalar S256) -> packed Z for ifft256.
__device__ __forceinline__ void half_to_z(f2* S, float S256,
                                          const float* twHc, const f2* twHn,
                                          int lane, int pl0, int plx) {
  f2 P[4];
  P[0] = shfl2(S[0], pl0);
#pragma unroll
  for (int b = 1; b < 4; ++b) P[b] = shfl2(S[4 - b], plx);
  P[0] = (lane == 0) ? (f2){S256, 0.0f} : P[0];
#pragma unroll
  for (int b = 0; b < 4; ++b) {
    f2 cP = conjf2(P[b]);
    f2 A = 0.5f * (S[b] + cP);
    f2 B = 0.5f * (S[b] - cP);
    f2 Bt = cmulp(B, twHc[b], twHn[b]);   // B * e^{+i th}
    S[b] = addi(A, Bt);
  }
}

// Per-bin mode update exploiting Hermitian symmetry (no cross-lane ops).
__device__ __forceinline__ void mode_update4(const f2* X, const f2* V, f2* U,
                                             const float* lam1, const float* lam2,
                                             float om, float f0) {
#pragma unroll
  for (int b = 0; b < 4; ++b) {
    float f = f0 + (float)b * (1.0f / 512.0f);
    float dfp = f - om;
    float dfm = f + om;
    float gp = __builtin_amdgcn_rcpf(fmaf(1600.0f * dfp, dfp, 1.0f));
    float gm = __builtin_amdgcn_rcpf(fmaf(1600.0f * dfm, dfm, 1.0f));
    float gs = 0.5f * (gp + gm);
    f2 D = X[b] - V[b];
    float lt = 0.25f * fmaf(lam1[b], gp, lam2[b] * gm);
    U[b] = gs * D + (f2){lt, 0.0f};
  }
}

// One wave per (b,d) sequence. SESSION-BEST VERIFIED (229.5 us total):
// DPP wave-sum (zero DS), xor4 via 2xDPP, rcp omega divide, lane-masked
// twiddles, pk-packed complex math, fused order+swap+zero epilogue kernel.
// CEILING EVIDENCE (this session, all counter-verified):
//  - r3: -10-15% VALU ops -> time FLAT at 200us (not issue-throughput-bound)
//  - r1: H>=16 exchanges DS->VALU permlane -> +24us (VALU is the scarcer pipe)
//  - r2: freq-domain lambda (deletes per-iter ifft) -> WRONG (ref adds
//    time-domain lam directly onto spectrum; ifft per iter is semantic)
//  - r4-r7: 2-waves/seq split (8192 waves): spill 780 -> conflicts 315 ->
//    re-spill 315 -> clean 252us. Barriers + doubled reductions + exchange
//    traffic exceed the TLP gain. Falsified at the r7 gate.
// Remaining ~29% non-VALU-busy margin = serial latency chain (lambda LDS ->
// modes -> wave_sums -> half_to_z -> 6 FFT stages -> lambda) x DS-pipe
// co-load at the 16-waves/CU cap (4096 seqs x 1 wave, barrier-free loop).
// NOTE (r17, prev session): in-kernel spin-sync fusion REGRESSED (+17us);
// the tiny epi dispatch (~5us, HBM-bound) is cheaper. Keep two kernels.
__global__ __attribute__((amdgpu_flat_work_group_size(256, 256),
                          amdgpu_waves_per_eu(4, 4),
                          amdgpu_num_vgpr(96)))
void vmd_kernel(const float* __restrict__ x, float* __restrict__ out,
                float* __restrict__ ws) {
  __shared__ float stage[4 * 512];    // [seq][n]; x resident during loop, reused for out
  __shared__ float ldsLam[4 * 512];   // psi-permuted lambda per wave

  const int tid = threadIdx.x;
  const int wv = tid >> 6;
  const int lane = tid & 63;
  const int w = (blockIdx.x >> 3) + ((blockIdx.x & 7) << 7);   // XCD swizzle
  const int g = 4 * w + wv;
  const int bb = w >> 5;
  const int d0 = (4 * w) & 127;
  const int base4 = bb * 16384 + (d0 >> 2);
  float* lamLds = ldsLam + wv * 512;
  f2* stg2 = (f2*)stage + wv * 256;   // packed (even,odd) pair view of this seq

  const int rev = (int)(__brev((unsigned)lane) >> 26);           // rev6(lane)
  const float f0 = (float)rev * (1.0f / 128.0f);
  const int plx = lane ^ 63;
  const int pl0 = (int)(__brev((unsigned)((64 - rev) & 63)) >> 26);

  // Stage twiddles, lane-masked: lo lanes = identity (wr=1, wn=0).
  float wrS[6], sgS[6]; f2 wnS[6];
#pragma unroll
  for (int s = 0; s < 6; ++s) {
    const int h = 32 >> s;
    const bool hi = (lane & h) != 0;
    float th = (float)(lane & (h - 1)) * (3.14159265358979323846f / (float)h);
    float sn, cs; sincosf(th, &sn, &cs);
    wrS[s] = hi ? cs : 1.0f;                        // W = e^{-i th}
    wnS[s] = hi ? (f2){sn, -sn} : (f2){0.0f, 0.0f};
    sgS[s] = hi ? -1.0f : 1.0f;
  }
  float twFc[3]; f2 twFn[3];
#pragma unroll
  for (int b = 1; b < 4; ++b) {
    float th = (float)(lane * b) * 0.02454369260617026f;   // 2pi/256, e^{-i th}
    float sn, cs; sincosf(th, &sn, &cs);
    twFc[b-1] = cs; twFn[b-1] = (f2){sn, -sn};
  }
  float twHc[4]; f2 twHn[4];
#pragma unroll
  for (int b = 0; b < 4; ++b) {
    float th = (float)(4 * rev + b) * 0.01227184630308513f; // 2pi/512, e^{+i th}
    float sn, cs; sincosf(th, &sn, &cs);
    twHc[b] = cs; twHn[b] = (f2){-sn, sn};
  }

  // ---- load x: float4 (n, d0..d0+3) -> stage[seq][n]; zero lambda ----
  {
    const float4* x4 = (const float4*)x;
    float4 va = x4[base4 + tid * 32];
    float4 vb = x4[base4 + (tid + 256) * 32];
    stage[tid]        = va.x; stage[512 + tid]        = va.y;
    stage[1024 + tid] = va.z; stage[1536 + tid]       = va.w;
    stage[tid + 256]        = vb.x; stage[512 + tid + 256]  = vb.y;
    stage[1024 + tid + 256] = vb.z; stage[1536 + tid + 256] = vb.w;
#pragma unroll
    for (int j = 0; j < 8; ++j) ldsLam[tid * 8 + j] = 0.0f;
  }
  __syncthreads();

  // ---- initial FFT input straight from LDS (x stays resident in stage) ----
  f2 z[4];
#pragma unroll
  for (int a = 0; a < 4; ++a) z[a] = stg2[64 * a + lane];
  fft256_fwd(z, twFc, twFn, wrS, wnS, sgS);
  f2 X[4];
  float X256;
  {
    f2 P[4];
    P[0] = shfl2(z[0], pl0);
#pragma unroll
    for (int b = 1; b < 4; ++b) P[b] = shfl2(z[4 - b], plx);
    X256 = bcast0(z[0].x - z[0].y);
#pragma unroll
    for (int b = 0; b < 4; ++b) {
      f2 cP = conjf2(P[b]);
      f2 E = 0.5f * (z[b] + cP);
      f2 O = 0.5f * (f2){1.0f, -1.0f} * swp(z[b] - cP);   // -i*(z-cP)/2
      X[b] = E + cmulpc(O, twHc[b], twHn[b]);             // O * e^{-i th}
    }
  }

  f2 U0[4], U1[4], lam[4];
#pragma unroll
  for (int b = 0; b < 4; ++b) {
    U0[b] = (f2){0.0f, 0.0f}; U1[b] = (f2){0.0f, 0.0f};
    lam[b] = (f2){0.0f, 0.0f};
  }
  float U0_256 = 0.0f, U1_256 = 0.0f;
  float om0 = 0.0f, om1 = 0.0f;

  const int psiE = 256 * (lane & 1) + (lane >> 1);   // lambda write base

#pragma unroll 1
  for (int it = 0; it < 50; ++it) {
    float lam1[4], lam2[4];
#pragma unroll
    for (int b = 0; b < 4; ++b) lam1[b] = lamLds[128 * b + 64 + rev];
    lam2[0] = lamLds[64 - rev];
#pragma unroll
    for (int b = 1; b < 4; ++b) lam2[b] = lamLds[128 * (4 - b) + 63 - rev];
    float lam0 = lamLds[0];

    mode_update4(X, U1, U0, lam1, lam2, om0, f0);
    {
      float dm = 0.5f + om0;
      float gg = __builtin_amdgcn_rcpf(fmaf(1600.0f * dm, dm, 1.0f));
      U0_256 = (X256 - U1_256 + 0.5f * lam0) * gg;
    }
    mode_update4(X, U0, U1, lam1, lam2, om1, f0);
    {
      float dm = 0.5f + om1;
      float gg = __builtin_amdgcn_rcpf(fmaf(1600.0f * dm, dm, 1.0f));
      U1_256 = (X256 - U0_256 + 0.5f * lam0) * gg;
    }

    // omega: per-bin accumulate, then pure-DPP wave sums (zero DS ops)
    f2 s0 = (f2){0.0f, 0.0f}, s1 = (f2){0.0f, 0.0f};
#pragma unroll
    for (int b = 0; b < 4; ++b) {
      float f = f0 + (float)b * (1.0f / 512.0f);
      float p0 = fmaf(U0[b].x, U0[b].x, U0[b].y * U0[b].y);
      float p1 = fmaf(U1[b].x, U1[b].x, U1[b].y * U1[b].y);
      s0 = s0 + (f2){f * p0, p0};
      s1 = s1 + (f2){f * p1, p1};
    }
    float n0 = wave_sum(s0.x), d0s = wave_sum(s0.y);
    float n1 = wave_sum(s1.x), d1s = wave_sum(s1.y);
    om0 = n0 * __builtin_amdgcn_rcpf(d0s + 1e-7f);
    om1 = n1 * __builtin_amdgcn_rcpf(d1s + 1e-7f);

    if (it < 49) {   // last iteration's lambda is never consumed
#pragma unroll
      for (int b = 0; b < 4; ++b) z[b] = U0[b] + U1[b];
      float S256 = U0_256 + U1_256;
      half_to_z(z, S256, twHc, twHn, lane, pl0, plx);
      ifft256(z, twFc, twFn, wrS, wnS, sgS);
#pragma unroll
      for (int a = 0; a < 4; ++a) {
        f2 xa = stg2[64 * a + lane];               // x from LDS
        lam[a] = lam[a] + 0.001f * (xa - z[a] * (1.0f / 256.0f));
        lamLds[psiE + 32 * a]       = lam[a].x;
        lamLds[psiE + 32 * a + 128] = lam[a].y;
      }
      asm volatile("s_waitcnt lgkmcnt(0)" ::: "memory");
    }
  }

  // ---- final modes: half->z, ifft256, pack to stage, float4 stores ----
  float4* o4 = (float4*)out;
#pragma unroll
  for (int b = 0; b < 4; ++b) z[b] = U0[b];
  half_to_z(z, U0_256, twHc, twHn, lane, pl0, plx);
  ifft256(z, twFc, twFn, wrS, wnS, sgS);
  __syncthreads();   // all waves done reading x from stage
#pragma unroll
  for (int a = 0; a < 4; ++a) stg2[64 * a + lane] = z[a] * (1.0f / 256.0f);
  __syncthreads();
#pragma unroll
  for (int r = 0; r < 2; ++r) {
    const int n = tid + r * 256;
    float4 v;
    v.x = stage[n]; v.y = stage[512 + n]; v.z = stage[1024 + n]; v.w = stage[1536 + n];
    o4[FIELD / 4 + base4 + n * 32] = v;
  }
  __syncthreads();
#pragma unroll
  for (int b = 0; b < 4; ++b) z[b] = U1[b];
  half_to_z(z, U1_256, twHc, twHn, lane, pl0, plx);
  ifft256(z, twFc, twFn, wrS, wnS, sgS);
#pragma unroll
  for (int a = 0; a < 4; ++a) stg2[64 * a + lane] = z[a] * (1.0f / 256.0f);
  __syncthreads();
#pragma unroll
  for (int r = 0; r < 2; ++r) {
    const int n = tid + r * 256;
    float4 v;
    v.x = stage[n]; v.y = stage[512 + n]; v.z = stage[1024 + n]; v.w = stage[1536 + n];
    o4[2 * FIELD / 4 + base4 + n * 32] = v;
  }

  if (lane == 0) {
    ws[g] = om0;             // omega staging in workspace (read-only for epi)
    ws[NSEQ + g] = om1;
  }
}

// Fused epilogue: per-batch flag recomputed per block (64 ws reads + wave
// reduce), trend slice zeroed, period/res conditionally swapped.
__global__ __launch_bounds__(256) void epi_kernel(float* __restrict__ out,
                                                  const float* __restrict__ ws) {
  const int tid = threadIdx.x;
  const int blk = blockIdx.x;          // 0..2047; 64 blocks per batch
  const int bb = blk >> 6;
  __shared__ float flagS;
  if (tid < 64) {
    float o0 = ws[bb * 128 + tid] + ws[bb * 128 + 64 + tid];
    float o1 = ws[NSEQ + bb * 128 + tid] + ws[NSEQ + bb * 128 + 64 + tid];
#pragma unroll
    for (int off = 32; off >= 1; off >>= 1) {
      o0 += __shfl_xor(o0, off, 64);
      o1 += __shfl_xor(o1, off, 64);
    }
    if (tid == 0) flagS = (o0 > o1) ? 1.0f : 0.0f;   // swap iff mean0 > mean1
  }
  __syncthreads();
  const bool sw = flagS > 0.5f;
  float4* o4 = (float4*)out;
  const int i = blk * 256 + tid;       // float4 index within trend field
  o4[i] = (float4){0.0f, 0.0f, 0.0f, 0.0f};
  if (sw) {
    float4 p = o4[FIELD / 4 + i];
    float4 r = o4[2 * FIELD / 4 + i];
    o4[FIELD / 4 + i] = r;
    o4[2 * FIELD / 4 + i] = p;
  }
}

extern "C" void kernel_launch(void* const* d_in, const int* in_sizes, int n_in,
                              void* d_out, int out_size, void* d_ws, size_t ws_size,
                              hipStream_t stream) {
  (void)in_sizes; (void)n_in; (void)ws_size; (void)out_size;
  const float* x = (const float*)d_in[0];
  float* out = (float*)d_out;
  float* ws = (float*)d_ws;
  vmd_kernel<<<NSEQ / 4, 256, 0, stream>>>(x, out, ws);
  epi_kernel<<<FIELD / 1024, 256, 0, stream>>>(out, ws);
}